// Round 9
// baseline (3053.214 us; speedup 1.0000x reference)
//
#include <hip/hip_runtime.h>
#include <stdint.h>
#include <stddef.h>

typedef _Float16 f16;
typedef _Float16 f16x8 __attribute__((ext_vector_type(8)));
typedef float    f32x4 __attribute__((ext_vector_type(4)));

#define NB    16384   // batch
#define TT    100     // encoder steps
#define II    6       // input features
#define HH    128     // hidden
#define OLEN  20      // decoder steps
#define OO    2       // output features
#define RR    32      // batch rows per block (R25: 2 blocks/CU target)

// f16-element offsets into workspace (8 recurrent mats are [512][128] = 65536 f16)
#define OFF_WHH0   0
#define OFF_WIH1   65536
#define OFF_WHH1   131072
#define OFF_DWIH0  196608
#define OFF_DWHH0  262144
#define OFF_DWIH1  327680
#define OFF_DWHH1  393216
#define OFF_WIH0P  458752          // [512][8] zero-padded (K=6 -> 8), prescaled
#define OFF_FCW    462848          // [2][128], NOT prescaled
#define OFF_BIAS_B 926208          // byte offset: 4*512 f32 combined prescaled biases
#define WS_BYTES   934400

#define SWZ(r) (((r) & 15) << 3)   // f16-unit XOR swizzle for h tiles

__device__ __forceinline__ float exp2_(float x) {
#if __has_builtin(__builtin_amdgcn_exp2f)
    return __builtin_amdgcn_exp2f(x);
#else
    return exp2f(x);
#endif
}
__device__ __forceinline__ float rcp_(float x) {
#if __has_builtin(__builtin_amdgcn_rcpf)
    return __builtin_amdgcn_rcpf(x);
#else
    return 1.f / x;
#endif
}

// ---------------- weight prep: fp32 -> f16, gate-prescaled; fuse+prescale biases ----
// gate rows (i,f,o) scaled by -log2(e) so sigmoid(z) = rcp(1+exp2(u));
// gate rows (g)     scaled by 2*log2(e) so tanh(z) = 1 - 2*rcp(1+exp2(u)).
__global__ __launch_bounds__(256) void prep_kernel(
    const float* eWih0, const float* eWhh0, const float* eWih1, const float* eWhh1,
    const float* dWih0, const float* dWhh0, const float* dWih1, const float* dWhh1,
    const float* ebi0,  const float* ebh0,  const float* ebi1,  const float* ebh1,
    const float* dbi0,  const float* dbh0,  const float* dbi1,  const float* dbh1,
    const float* fcW,   f16* w16, float* bws)
{
    const float GS0 = -1.4426950408889634f;   // i, f, o
    const float GS2 =  2.8853900817779268f;   // g
    int i0 = blockIdx.x * blockDim.x + threadIdx.x;
    int stride = gridDim.x * blockDim.x;
    const float* srcs[7] = {eWhh0, eWih1, eWhh1, dWih0, dWhh0, dWih1, dWhh1};
    for (int i = i0; i < 7 * 65536; i += stride) {
        int rem = i & 65535;
        float s = ((rem >> 14) == 2) ? GS2 : GS0;
        w16[i] = (f16)(srcs[i >> 16][rem] * s);
    }
    for (int i = i0; i < 512 * 8; i += stride) {
        int n = i >> 3, k = i & 7;
        float s = ((n >> 7) == 2) ? GS2 : GS0;
        w16[OFF_WIH0P + i] = (k < II) ? (f16)(eWih0[n * II + k] * s) : (f16)0.f;
    }
    for (int i = i0; i < OO * HH; i += stride) w16[OFF_FCW + i] = (f16)fcW[i];
    const float* bia[4] = {ebi0, ebi1, dbi0, dbi1};
    const float* bib[4] = {ebh0, ebh1, dbh0, dbh1};
    for (int i = i0; i < 4 * 512; i += stride) {
        int j = i & 511;
        float s = ((j >> 7) == 2) ? GS2 : GS0;
        bws[i] = (bia[i >> 9][j] + bib[i >> 9][j]) * s;
    }
}

// ---------------- main persistent LSTM kernel: 1 block = 32 batch rows ----------------
// History: R16 1606us (pipelined regions); R23 1548us (half-bank + fc-fold) =
// best. R17 anti-phase regressed; R21/R22/R24 resident-bank & dual-acc all
// SPILL (envelope capped at ~128 arch + 64 acc); R18/R20 min-waves>=4 with
// >64-arch demand spill.
// R19 RE-DIAGNOSIS: RR=32 ran clean (arch 92 + acc 32 = 124) yet occupancy
// stayed 24% -- HW reg granularity is 64 (m69: waves halve at 64/128/256), so
// arch 92 -> 128-class -> 2 waves/SIMD. 4 waves/SIMD requires arch<=64 AND
// acc<=64. R19 also showed per-region time ~invariant to per-wave work:
// issue/latency-bound per wave -> two co-resident INDEPENDENT blocks co-issue
// VALU/trans of one with MFMA of the other (m114) and roughly sum pipe
// utilizations (both pipes < 45% at 2 blocks).
// R25: hit the <=64/<=64 shape. RR=32 (LDS 73.5KB -> 2 blocks/CU fit),
// bounds(512,4), streamed bank shrunk to a SINGLE QUARTER-BANK bank[4]
// (16 regs; each matrix = 4 bursts of 4 loads; per-slice latency exposure is
// covered by the other block's waves -- that's what the occupancy is FOR).
// Arch demand ~52 (qbank 16 + bX 16 + misc) <= 64; acc[4][2] = 32 <= 64.
// Unlike R18 (demand 112 under the same cap), demand fits with slack.
__global__ __launch_bounds__(512, 4) void lstm_kernel(
    const float* __restrict__ xg, const f16* __restrict__ wsf,
    const float* __restrict__ bws, const float* __restrict__ fcb,
    float* __restrict__ out)
{
    __shared__ __align__(16) f16 h0s[2][RR][HH];     // 16KB, XOR-swizzled
    __shared__ __align__(16) f16 h1s[2][RR][HH];     // 16KB
    __shared__ __align__(16) f16 xs[2][RR][8];       // 1KB
    __shared__ __align__(16) f16 fcws[OO * HH];      // .5KB
    __shared__ float bias_s[4 * 512];                // 8KB
    __shared__ f32x4 c0s[2][512];                    // 16KB cell-0 state (per-thread slots)
    __shared__ f32x4 c1s[2][512];                    // 16KB cell-1 state -> 73.5KB total

    const int tid = threadIdx.x;
    const int w   = tid >> 6;      // wave 0..7 -> hidden cols 16w..16w+15
    const int ln  = tid & 63;
    const int l15 = ln & 15;
    const int lg  = ln >> 4;       // lane k-group
    const int r0  = blockIdx.x * RR;

    // ---- init LDS (note: BOTH h1 buffers zeroed -- region 1 reads h1s[1] as h1(-1))
    for (int i = tid; i < OO * HH; i += 512) fcws[i] = wsf[OFF_FCW + i];
    for (int i = tid; i < 4 * 512; i += 512) bias_s[i] = bws[i];
    for (int i = tid; i < RR * HH; i += 512) {
        h0s[0][0][i] = (f16)0.f;
        h0s[1][0][i] = (f16)0.f;
        h1s[0][0][i] = (f16)0.f;
        h1s[1][0][i] = (f16)0.f;
    }
    {
        const f32x4 z4 = {0.f, 0.f, 0.f, 0.f};
        for (int i = tid; i < 2 * 512; i += 512) {
            (&c0s[0][0])[i] = z4;
            (&c1s[0][0])[i] = z4;
        }
    }
    if (tid < RR * 8) {   // stage x[t=0]
        int r = tid >> 3, k = tid & 7;
        float v = (k < II) ? xg[((size_t)(r0 + r) * TT + 0) * II + k] : 0.f;
        xs[0][r][k] = (f16)v;
    }

    f32x4 acc[4][2];   // [gate][m] accumulators (32 regs, acc side)
    f16x8 bank[4];     // [gate] single streamed QUARTER-bank (16 arch regs)
    f16x8 bX[4];       // encoder x-weights (16 arch regs; zero in lanes lg>0)

    {
        const f16x8 z = {};
        #pragma unroll
        for (int g = 0; g < 4; ++g) {
            const int nt = (g << 3) + w;
            bX[g] = (lg == 0)
                ? *(const f16x8*)(wsf + OFF_WIH0P + (size_t)((nt << 4) + l15) * 8)
                : z;
        }
    }

    // stream ONE kk-slice of one matrix into the quarter-bank (4 loads).
    // Offset tied through an empty asm so loads re-execute per call (no
    // hoisting into a persistent spill-prone set -- the R5-R11 failure mode).
    auto loadQ = [&](unsigned offElems, int kk) {
        unsigned off = offElems + (unsigned)(kk << 5);
        asm volatile("" : "+v"(off));
        const f16* W = wsf + off;
        #pragma unroll
        for (int g = 0; g < 4; ++g) {
            const int nt = (g << 3) + w;
            bank[g] = *(const f16x8*)(W + (size_t)((nt << 4) + l15) * HH + (lg << 3));
        }
    };
    // fence + load: sched_barrier stops the new slice's loads from hoisting
    // above the previous slice's MFMAs (liveness doubling).
    #define LQ(off, kk) do { __builtin_amdgcn_sched_barrier(0); loadQ(off, kk); } while (0)

    auto zacc = [&](int cell) {
        #pragma unroll
        for (int g = 0; g < 4; ++g) {
            float b = bias_s[(cell << 9) | (g << 7) | (w << 4) | l15];
            f32x4 b4 = {b, b, b, b};
            #pragma unroll
            for (int m = 0; m < 2; ++m) acc[g][m] = b4;
        }
    };

    // K=32 slice-GEMM over both m-tiles with the current quarter-bank
    auto kq = [&](const f16* hsrc, int kk) {
        #pragma unroll
        for (int m = 0; m < 2; ++m) {
            int r = (m << 4) + l15;
            int c = ((kk << 5) | (lg << 3)) ^ SWZ(r);
            f16x8 a = *(const f16x8*)(hsrc + (size_t)r * HH + c);
            #pragma unroll
            for (int g = 0; g < 4; ++g)
                acc[g][m] = __builtin_amdgcn_mfma_f32_16x16x32_f16(a, bank[g], acc[g][m], 0, 0, 0);
        }
    };

    // encoder x-term: zero-padded K=32 MFMA (real K=6 in lanes lg==0); no bank dep
    auto mfx = [&](const f16 (*xsrc)[8]) {
        const f16x8 z = {};
        #pragma unroll
        for (int m = 0; m < 2; ++m) {
            int r = (m << 4) + l15;
            f16x8 a = lg ? z : *(const f16x8*)(&xsrc[r][0]);
            #pragma unroll
            for (int g = 0; g < 4; ++g)
                acc[g][m] = __builtin_amdgcn_mfma_f32_16x16x32_f16(a, bX[g], acc[g][m], 0, 0, 0);
        }
    };

    // gate nonlinearities; c in per-thread LDS slots; h -> hdst (parity-[p^1]
    // buffer, never read in the same region -> race-free).
    auto act = [&](f32x4 (*cs)[512], f16* hdst) {
        const int col = (w << 4) + l15;
        #pragma unroll
        for (int m = 0; m < 2; ++m) {
            f32x4 cold = cs[m][tid];
            f32x4 cnew;
            #pragma unroll
            for (int q = 0; q < 4; ++q) {
                float si = rcp_(1.f + exp2_(acc[0][m][q]));
                float sf = rcp_(1.f + exp2_(acc[1][m][q]));
                float tg = 1.f - 2.f * rcp_(1.f + exp2_(acc[2][m][q]));
                float so = rcp_(1.f + exp2_(acc[3][m][q]));
                float cn = sf * cold[q] + si * tg;
                cnew[q] = cn;
                float hn = so * (1.f - 2.f * rcp_(1.f + exp2_(2.8853900817779268f * cn)));
                int r = (m << 4) + (lg << 2) + q;
                hdst[(size_t)r * HH + (col ^ SWZ(r))] = (f16)hn;
            }
            cs[m][tid] = cnew;
        }
    };

    LQ(OFF_WHH0, 0);     // prologue: region 0's first slice
    __syncthreads();     // init visible

    // ============ encoder: 100 pipelined regions + tail, 1 barrier each ============
    // region t: phaseA(t):  gates0 = b0 + x(t)*Wih0 + h0s[p]*Whh0 -> h0s[p^1], c0
    //           phaseB(t-1):gates1 = b1 + h1s[p]*Whh1 + h0s[p]*Wih1 -> h1s[p^1], c1
    // (h0(t-1) lives in h0s[p]; h1(t-2) in h1s[p] -- all reads pre-region.)
    // Each matrix streams as 4 slice-bursts of 4 loads; per-slice latency is
    // covered by the co-resident block's waves (4 waves/SIMD).
    for (int t = 0; t < TT; ++t) {
        const int p = t & 1;
        float xv = 0.f;
        if (t + 1 < TT && tid < RR * 8 && (tid & 7) < II)
            xv = xg[((size_t)(r0 + (tid >> 3)) * TT + (t + 1)) * II + (tid & 7)];
        // phase A (slice 0 preloaded at end of previous region)
        zacc(0);
        mfx(xs[p]);
        kq(&h0s[p][0][0], 0);
        LQ(OFF_WHH0, 1); kq(&h0s[p][0][0], 1);
        LQ(OFF_WHH0, 2); kq(&h0s[p][0][0], 2);
        LQ(OFF_WHH0, 3); kq(&h0s[p][0][0], 3);
        if (t > 0) {
            LQ(OFF_WHH1, 0);                 // B's first slice streams under act0
            act(c0s, &h0s[p ^ 1][0][0]);
            zacc(1);
            kq(&h1s[p][0][0], 0);            // state term h1(t-2)
            LQ(OFF_WHH1, 1); kq(&h1s[p][0][0], 1);
            LQ(OFF_WHH1, 2); kq(&h1s[p][0][0], 2);
            LQ(OFF_WHH1, 3); kq(&h1s[p][0][0], 3);
            LQ(OFF_WIH1, 0); kq(&h0s[p][0][0], 0);   // input term h0(t-1) (OLD buffer)
            LQ(OFF_WIH1, 1); kq(&h0s[p][0][0], 1);
            LQ(OFF_WIH1, 2); kq(&h0s[p][0][0], 2);
            LQ(OFF_WIH1, 3); kq(&h0s[p][0][0], 3);
            LQ(OFF_WHH0, 0);                 // next region's A preload, under act1
            act(c1s, &h1s[p ^ 1][0][0]);     // h1(t-1)
        } else {
            LQ(OFF_WHH0, 0);                 // region 1's A preload, under act0
            act(c0s, &h0s[p ^ 1][0][0]);
        }
        if (t + 1 < TT && tid < RR * 8) xs[p ^ 1][tid >> 3][tid & 7] = (f16)xv;
        __builtin_amdgcn_sched_barrier(0);
        __syncthreads();                 // ONE barrier per region
    }
    // tail region: phaseB(99). After loop: h0(99)=h0s[0], h1(98)=h1s[0].
    // (bank holds a dead WHH0-0 preload from t=99 -- 4 wasted loads, harmless.)
    {
        LQ(OFF_WHH1, 0);
        zacc(1);
        kq(&h1s[0][0][0], 0);            // h1(98)
        LQ(OFF_WHH1, 1); kq(&h1s[0][0][0], 1);
        LQ(OFF_WHH1, 2); kq(&h1s[0][0][0], 2);
        LQ(OFF_WHH1, 3); kq(&h1s[0][0][0], 3);
        LQ(OFF_WIH1, 0); kq(&h0s[0][0][0], 0);   // h0(99)
        LQ(OFF_WIH1, 1); kq(&h0s[0][0][0], 1);
        LQ(OFF_WIH1, 2); kq(&h0s[0][0][0], 2);
        LQ(OFF_WIH1, 3); kq(&h0s[0][0][0], 3);
        LQ(OFF_DWHH0, 0);                // decoder phase-A preload, under act1
        act(c1s, &h1s[1][0][0]);         // h1(99) -> h1s[1]
        __builtin_amdgcn_sched_barrier(0);
        __syncthreads();
    }
    // decoder entry: h0 cur = h0s[0], h1 cur = h1s[1]

    float fb = (tid < RR * OO) ? fcb[tid & 1] : 0.f;

    // fc: pred[r][o] = h1d(s) . fc_W[o] + fc_b[o]  (threads 0..63 only)
    auto fcOut = [&](int s, int qq) {
        if (tid < RR * OO) {
            int r = tid >> 1, o = tid & 1;
            float a = fb;
            const f16* hrow = &h1s[qq][r][0];
            #pragma unroll
            for (int ccol = 0; ccol < HH; ccol += 8) {
                int csw = ccol ^ SWZ(r);
                f16x8 hv = *(const f16x8*)(hrow + csw);
                f16x8 wv = *(const f16x8*)(&fcws[o * HH + ccol]);
                #pragma unroll
                for (int j = 0; j < 8; ++j) a += (float)hv[j] * (float)wv[j];
            }
            out[((size_t)(r0 + r) * OLEN + s) * OO + o] = a;
        }
    };

    // ============ decoder: 20 steps, 2 barriers/step ============
    // step s (q=s&1): reads h0s[q], h1s[q^1]; writes h0s[q^1] (A), h1s[q] (B).
    // Strictly serial (B(s) needs A(s)'s h0 through the barrier). fc(s-1)
    // folded into A(s): reads h1s[q^1] (A-read-only; next written B(s+1)).
    for (int s = 0; s < OLEN; ++s) {
        const int q = s & 1;
        // Phase A: gates2 = b2 + h0d(s-1)*DWhh0 + h1d(s-1)*DWih0 -> h0d(s)
        zacc(2);
        if (s > 0) fcOut(s - 1, q ^ 1);  // waves 0-1 do fc; waves 2-7 proceed
        kq(&h0s[q][0][0], 0);            // DWHH0-0 (preloaded)
        LQ(OFF_DWHH0, 1); kq(&h0s[q][0][0], 1);
        LQ(OFF_DWHH0, 2); kq(&h0s[q][0][0], 2);
        LQ(OFF_DWHH0, 3); kq(&h0s[q][0][0], 3);
        LQ(OFF_DWIH0, 0); kq(&h1s[q ^ 1][0][0], 0);
        LQ(OFF_DWIH0, 1); kq(&h1s[q ^ 1][0][0], 1);
        LQ(OFF_DWIH0, 2); kq(&h1s[q ^ 1][0][0], 2);
        LQ(OFF_DWIH0, 3); kq(&h1s[q ^ 1][0][0], 3);
        LQ(OFF_DWHH1, 0);                // phase-B preload, under actA
        act(c0s, &h0s[q ^ 1][0][0]);
        __builtin_amdgcn_sched_barrier(0);
        __syncthreads();                 // BAR1: h0d(s) published
        // Phase B: gates3 = b3 + h1d(s-1)*DWhh1 + h0d(s)*DWih1 -> h1d(s)
        zacc(3);
        kq(&h1s[q ^ 1][0][0], 0);        // DWHH1-0 (preloaded)
        LQ(OFF_DWHH1, 1); kq(&h1s[q ^ 1][0][0], 1);
        LQ(OFF_DWHH1, 2); kq(&h1s[q ^ 1][0][0], 2);
        LQ(OFF_DWHH1, 3); kq(&h1s[q ^ 1][0][0], 3);
        LQ(OFF_DWIH1, 0); kq(&h0s[q ^ 1][0][0], 0);
        LQ(OFF_DWIH1, 1); kq(&h0s[q ^ 1][0][0], 1);
        LQ(OFF_DWIH1, 2); kq(&h0s[q ^ 1][0][0], 2);
        LQ(OFF_DWIH1, 3); kq(&h0s[q ^ 1][0][0], 3);
        LQ(OFF_DWHH0, 0);                // next step's A preload (dead at s=19, harmless)
        act(c1s, &h1s[q][0][0]);
        __builtin_amdgcn_sched_barrier(0);
        __syncthreads();                 // BAR2: h1d(s) published
    }
    fcOut(OLEN - 1, (OLEN - 1) & 1);     // last step's fc
    #undef LQ
}

extern "C" void kernel_launch(void* const* d_in, const int* in_sizes, int n_in,
                              void* d_out, int out_size, void* d_ws, size_t ws_size,
                              hipStream_t stream) {
    const float* x     = (const float*)d_in[0];
    const float* eWih0 = (const float*)d_in[1];
    const float* eWhh0 = (const float*)d_in[2];
    const float* ebi0  = (const float*)d_in[3];
    const float* ebh0  = (const float*)d_in[4];
    const float* eWih1 = (const float*)d_in[5];
    const float* eWhh1 = (const float*)d_in[6];
    const float* ebi1  = (const float*)d_in[7];
    const float* ebh1  = (const float*)d_in[8];
    const float* dWih0 = (const float*)d_in[9];
    const float* dWhh0 = (const float*)d_in[10];
    const float* dbi0  = (const float*)d_in[11];
    const float* dbh0  = (const float*)d_in[12];
    const float* dWih1 = (const float*)d_in[13];
    const float* dWhh1 = (const float*)d_in[14];
    const float* dbi1  = (const float*)d_in[15];
    const float* dbh1  = (const float*)d_in[16];
    const float* fcW   = (const float*)d_in[17];
    const float* fcb   = (const float*)d_in[18];

    f16*   w16 = (f16*)d_ws;
    float* bws = (float*)((char*)d_ws + OFF_BIAS_B);

    prep_kernel<<<256, 256, 0, stream>>>(eWih0, eWhh0, eWih1, eWhh1,
                                         dWih0, dWhh0, dWih1, dWhh1,
                                         ebi0, ebh0, ebi1, ebh1,
                                         dbi0, dbh0, dbi1, dbh1,
                                         fcW, w16, bws);
    lstm_kernel<<<NB / RR, 512, 0, stream>>>(x, w16, bws, fcb, (float*)d_out);
}

// Round 10
// 2873.884 us; speedup vs baseline: 1.0624x; 1.0624x over previous
//
#include <hip/hip_runtime.h>
#include <stdint.h>
#include <stddef.h>

typedef _Float16 f16;
typedef _Float16 f16x8 __attribute__((ext_vector_type(8)));
typedef float    f32x4 __attribute__((ext_vector_type(4)));

#define NB    16384   // batch
#define TT    100     // encoder steps
#define II    6       // input features
#define HH    128     // hidden
#define OLEN  20      // decoder steps
#define OO    2       // output features
#define RR    32      // batch rows per block (2 blocks/CU)

// f16-element offsets into workspace (8 recurrent mats are [512][128] = 65536 f16)
#define OFF_WHH0   0
#define OFF_WIH1   65536
#define OFF_WHH1   131072
#define OFF_DWIH0  196608
#define OFF_DWHH0  262144
#define OFF_DWIH1  327680
#define OFF_DWHH1  393216
#define OFF_WIH0P  458752          // [512][8] zero-padded (K=6 -> 8), prescaled
#define OFF_FCW    462848          // [2][128], NOT prescaled
#define OFF_BIAS_B 926208          // byte offset: 4*512 f32 combined prescaled biases
#define WS_BYTES   934400

#define SWZ(r) (((r) & 15) << 3)   // f16-unit XOR swizzle for h tiles

__device__ __forceinline__ float exp2_(float x) {
#if __has_builtin(__builtin_amdgcn_exp2f)
    return __builtin_amdgcn_exp2f(x);
#else
    return exp2f(x);
#endif
}
__device__ __forceinline__ float rcp_(float x) {
#if __has_builtin(__builtin_amdgcn_rcpf)
    return __builtin_amdgcn_rcpf(x);
#else
    return 1.f / x;
#endif
}

// ---------------- weight prep: fp32 -> f16, gate-prescaled; fuse+prescale biases ----
// gate rows (i,f,o) scaled by -log2(e) so sigmoid(z) = rcp(1+exp2(u));
// gate rows (g)     scaled by 2*log2(e) so tanh(z) = 1 - 2*rcp(1+exp2(u)).
__global__ __launch_bounds__(256) void prep_kernel(
    const float* eWih0, const float* eWhh0, const float* eWih1, const float* eWhh1,
    const float* dWih0, const float* dWhh0, const float* dWih1, const float* dWhh1,
    const float* ebi0,  const float* ebh0,  const float* ebi1,  const float* ebh1,
    const float* dbi0,  const float* dbh0,  const float* dbi1,  const float* dbh1,
    const float* fcW,   f16* w16, float* bws)
{
    const float GS0 = -1.4426950408889634f;   // i, f, o
    const float GS2 =  2.8853900817779268f;   // g
    int i0 = blockIdx.x * blockDim.x + threadIdx.x;
    int stride = gridDim.x * blockDim.x;
    const float* srcs[7] = {eWhh0, eWih1, eWhh1, dWih0, dWhh0, dWih1, dWhh1};
    for (int i = i0; i < 7 * 65536; i += stride) {
        int rem = i & 65535;
        float s = ((rem >> 14) == 2) ? GS2 : GS0;
        w16[i] = (f16)(srcs[i >> 16][rem] * s);
    }
    for (int i = i0; i < 512 * 8; i += stride) {
        int n = i >> 3, k = i & 7;
        float s = ((n >> 7) == 2) ? GS2 : GS0;
        w16[OFF_WIH0P + i] = (k < II) ? (f16)(eWih0[n * II + k] * s) : (f16)0.f;
    }
    for (int i = i0; i < OO * HH; i += stride) w16[OFF_FCW + i] = (f16)fcW[i];
    const float* bia[4] = {ebi0, ebi1, dbi0, dbi1};
    const float* bib[4] = {ebh0, ebh1, dbh0, dbh1};
    for (int i = i0; i < 4 * 512; i += stride) {
        int j = i & 511;
        float s = ((j >> 7) == 2) ? GS2 : GS0;
        bws[i] = (bia[i >> 9][j] + bib[i >> 9][j]) * s;
    }
}

// ---------------- main persistent LSTM kernel: 1 block = 32 batch rows ----------------
// History: R23 (half-bank + fc-fold, RR=64, 2 waves/SIMD) = 1548us best.
// R25 (RR=32, bounds(512,4), quarter-bank): OCCUPANCY 45% ACHIEVED (4
// waves/SIMD, granule-64 model confirmed: arch<=64 AND acc<=64 needed) but
// spilled -- acc MUST be arch-side (VALU in act() reads it; AGPRs aren't
// VALU-readable), so demand was acc32+bank16+bX16+misc ~84 > 64.
// R26: fit arch <=64 for real. (a) bX ELIMINATED -> Wih0P fragments live in
// LDS (wih0p[513][8], row 512 = zeros; lg>0 lanes read the zero row via a
// broadcast -- B=0 makes the product zero, A read unconditionally); mfx reads
// 4 B-frags per region from near-idle LDS. (b) bias_s shrunk to 2 cells
// (4KB), decoder cells reloaded at decoder entry (+1 barrier). LDS 77.5KB ->
// 2 blocks/CU = 155KB <= 160. (c) streamed-bank offset tie moved "+v"->"+s"
// (SALU addressing). Arch ledger: acc 32 + bank 16 (MFMA-B-only, may go
// AGPR) + misc ~12 ~= 60 <= 64. Payoff per R19: region cost is per-wave
// issue/latency; two INDEPENDENT co-resident blocks overlap each other's
// stalls (m114); both pipes <45% so summing has headroom.
__global__ __launch_bounds__(512, 4) void lstm_kernel(
    const float* __restrict__ xg, const f16* __restrict__ wsf,
    const float* __restrict__ bws, const float* __restrict__ fcb,
    float* __restrict__ out)
{
    __shared__ __align__(16) f16 h0s[2][RR][HH];     // 16KB, XOR-swizzled
    __shared__ __align__(16) f16 h1s[2][RR][HH];     // 16KB
    __shared__ __align__(16) f16 xs[2][RR][8];       // 1KB
    __shared__ __align__(16) f16 fcws[OO * HH];      // .5KB
    __shared__ __align__(16) f16 wih0p[513 * 8];     // 8KB (+16B zero row)
    __shared__ float bias_s[2 * 512];                // 4KB (2 cells at a time)
    __shared__ f32x4 c0s[2][512];                    // 16KB cell-0 state (per-thread slots)
    __shared__ f32x4 c1s[2][512];                    // 16KB cell-1 state -> 77.5KB total

    const int tid = threadIdx.x;
    const int w   = tid >> 6;      // wave 0..7 -> hidden cols 16w..16w+15
    const int ln  = tid & 63;
    const int l15 = ln & 15;
    const int lg  = ln >> 4;       // lane k-group
    const int r0  = blockIdx.x * RR;

    // ---- init LDS (note: BOTH h1 buffers zeroed -- region 1 reads h1s[1] as h1(-1))
    for (int i = tid; i < OO * HH; i += 512) fcws[i] = wsf[OFF_FCW + i];
    for (int i = tid; i < 2 * 512; i += 512) bias_s[i] = bws[i];      // encoder cells 0,1
    for (int i = tid; i < 513 * 8; i += 512)
        wih0p[i] = (i < 512 * 8) ? wsf[OFF_WIH0P + i] : (f16)0.f;
    for (int i = tid; i < RR * HH; i += 512) {
        h0s[0][0][i] = (f16)0.f;
        h0s[1][0][i] = (f16)0.f;
        h1s[0][0][i] = (f16)0.f;
        h1s[1][0][i] = (f16)0.f;
    }
    {
        const f32x4 z4 = {0.f, 0.f, 0.f, 0.f};
        for (int i = tid; i < 2 * 512; i += 512) {
            (&c0s[0][0])[i] = z4;
            (&c1s[0][0])[i] = z4;
        }
    }
    if (tid < RR * 8) {   // stage x[t=0]
        int r = tid >> 3, k = tid & 7;
        float v = (k < II) ? xg[((size_t)(r0 + r) * TT + 0) * II + k] : 0.f;
        xs[0][r][k] = (f16)v;
    }

    f32x4 acc[4][2];   // [gate][m] accumulators (32 arch regs -- VALU-read in act)
    f16x8 bank[4];     // [gate] single streamed QUARTER-bank (16 regs, MFMA-B only)

    // stream ONE kk-slice of one matrix into the quarter-bank (4 loads).
    // Offset tied through an empty asm ("+s": stays in SALU) so loads
    // re-execute per call (no hoisting into a persistent spill-prone set).
    auto loadQ = [&](unsigned offElems, int kk) {
        unsigned off = offElems + (unsigned)(kk << 5);
        asm volatile("" : "+s"(off));
        const f16* W = wsf + off;
        #pragma unroll
        for (int g = 0; g < 4; ++g) {
            const int nt = (g << 3) + w;
            bank[g] = *(const f16x8*)(W + (size_t)((nt << 4) + l15) * HH + (lg << 3));
        }
    };
    // fence + load: sched_barrier stops the new slice's loads from hoisting
    // above the previous slice's MFMAs (liveness doubling).
    #define LQ(off, kk) do { __builtin_amdgcn_sched_barrier(0); loadQ(off, kk); } while (0)

    auto zacc = [&](int cellHalf) {   // 0/1 = which half of the resident bias pair
        #pragma unroll
        for (int g = 0; g < 4; ++g) {
            float b = bias_s[(cellHalf << 9) | (g << 7) | (w << 4) | l15];
            f32x4 b4 = {b, b, b, b};
            #pragma unroll
            for (int m = 0; m < 2; ++m) acc[g][m] = b4;
        }
    };

    // K=32 slice-GEMM over both m-tiles with the current quarter-bank
    auto kq = [&](const f16* hsrc, int kk) {
        #pragma unroll
        for (int m = 0; m < 2; ++m) {
            int r = (m << 4) + l15;
            int c = ((kk << 5) | (lg << 3)) ^ SWZ(r);
            f16x8 a = *(const f16x8*)(hsrc + (size_t)r * HH + c);
            #pragma unroll
            for (int g = 0; g < 4; ++g)
                acc[g][m] = __builtin_amdgcn_mfma_f32_16x16x32_f16(a, bank[g], acc[g][m], 0, 0, 0);
        }
    };

    // encoder x-term: zero-padded K=32 MFMA. B-fragment from LDS (lg>0 lanes
    // read the shared zero row -> product zero; A read unconditionally).
    auto mfx = [&](const f16 (*xsrc)[8]) {
        #pragma unroll
        for (int g = 0; g < 4; ++g) {
            const int nt = (g << 3) + w;
            int row = (lg == 0) ? ((nt << 4) + l15) : 512;
            f16x8 bx = *(const f16x8*)(&wih0p[row * 8]);
            #pragma unroll
            for (int m = 0; m < 2; ++m) {
                int r = (m << 4) + l15;
                f16x8 a = *(const f16x8*)(&xsrc[r][0]);
                acc[g][m] = __builtin_amdgcn_mfma_f32_16x16x32_f16(a, bx, acc[g][m], 0, 0, 0);
            }
        }
    };

    // gate nonlinearities; c in per-thread LDS slots; h -> hdst (parity-[p^1]
    // buffer, never read in the same region -> race-free).
    auto act = [&](f32x4 (*cs)[512], f16* hdst) {
        const int col = (w << 4) + l15;
        #pragma unroll
        for (int m = 0; m < 2; ++m) {
            f32x4 cold = cs[m][tid];
            f32x4 cnew;
            #pragma unroll
            for (int q = 0; q < 4; ++q) {
                float si = rcp_(1.f + exp2_(acc[0][m][q]));
                float sf = rcp_(1.f + exp2_(acc[1][m][q]));
                float tg = 1.f - 2.f * rcp_(1.f + exp2_(acc[2][m][q]));
                float so = rcp_(1.f + exp2_(acc[3][m][q]));
                float cn = sf * cold[q] + si * tg;
                cnew[q] = cn;
                float hn = so * (1.f - 2.f * rcp_(1.f + exp2_(2.8853900817779268f * cn)));
                int r = (m << 4) + (lg << 2) + q;
                hdst[(size_t)r * HH + (col ^ SWZ(r))] = (f16)hn;
            }
            cs[m][tid] = cnew;
        }
    };

    LQ(OFF_WHH0, 0);     // prologue: region 0's first slice
    __syncthreads();     // init visible

    // ============ encoder: 100 pipelined regions + tail, 1 barrier each ============
    // region t: phaseA(t):  gates0 = b0 + x(t)*Wih0 + h0s[p]*Whh0 -> h0s[p^1], c0
    //           phaseB(t-1):gates1 = b1 + h1s[p]*Whh1 + h0s[p]*Wih1 -> h1s[p^1], c1
    // (h0(t-1) lives in h0s[p]; h1(t-2) in h1s[p] -- all reads pre-region.)
    // Each matrix streams as 4 slice-bursts of 4 loads; per-slice latency is
    // covered by the co-resident block's waves (4 waves/SIMD).
    for (int t = 0; t < TT; ++t) {
        const int p = t & 1;
        float xv = 0.f;
        if (t + 1 < TT && tid < RR * 8 && (tid & 7) < II)
            xv = xg[((size_t)(r0 + (tid >> 3)) * TT + (t + 1)) * II + (tid & 7)];
        // phase A (slice 0 preloaded at end of previous region)
        zacc(0);
        mfx(xs[p]);
        kq(&h0s[p][0][0], 0);
        LQ(OFF_WHH0, 1); kq(&h0s[p][0][0], 1);
        LQ(OFF_WHH0, 2); kq(&h0s[p][0][0], 2);
        LQ(OFF_WHH0, 3); kq(&h0s[p][0][0], 3);
        if (t > 0) {
            LQ(OFF_WHH1, 0);                 // B's first slice streams under act0
            act(c0s, &h0s[p ^ 1][0][0]);
            zacc(1);
            kq(&h1s[p][0][0], 0);            // state term h1(t-2)
            LQ(OFF_WHH1, 1); kq(&h1s[p][0][0], 1);
            LQ(OFF_WHH1, 2); kq(&h1s[p][0][0], 2);
            LQ(OFF_WHH1, 3); kq(&h1s[p][0][0], 3);
            LQ(OFF_WIH1, 0); kq(&h0s[p][0][0], 0);   // input term h0(t-1) (OLD buffer)
            LQ(OFF_WIH1, 1); kq(&h0s[p][0][0], 1);
            LQ(OFF_WIH1, 2); kq(&h0s[p][0][0], 2);
            LQ(OFF_WIH1, 3); kq(&h0s[p][0][0], 3);
            LQ(OFF_WHH0, 0);                 // next region's A preload, under act1
            act(c1s, &h1s[p ^ 1][0][0]);     // h1(t-1)
        } else {
            LQ(OFF_WHH0, 0);                 // region 1's A preload, under act0
            act(c0s, &h0s[p ^ 1][0][0]);
        }
        if (t + 1 < TT && tid < RR * 8) xs[p ^ 1][tid >> 3][tid & 7] = (f16)xv;
        __builtin_amdgcn_sched_barrier(0);
        __syncthreads();                 // ONE barrier per region
    }
    // tail region: phaseB(99). After loop: h0(99)=h0s[0], h1(98)=h1s[0].
    {
        LQ(OFF_WHH1, 0);
        zacc(1);
        kq(&h1s[0][0][0], 0);            // h1(98)
        LQ(OFF_WHH1, 1); kq(&h1s[0][0][0], 1);
        LQ(OFF_WHH1, 2); kq(&h1s[0][0][0], 2);
        LQ(OFF_WHH1, 3); kq(&h1s[0][0][0], 3);
        LQ(OFF_WIH1, 0); kq(&h0s[0][0][0], 0);   // h0(99)
        LQ(OFF_WIH1, 1); kq(&h0s[0][0][0], 1);
        LQ(OFF_WIH1, 2); kq(&h0s[0][0][0], 2);
        LQ(OFF_WIH1, 3); kq(&h0s[0][0][0], 3);
        LQ(OFF_DWHH0, 0);                // decoder phase-A preload, under act1
        act(c1s, &h1s[1][0][0]);         // h1(99) -> h1s[1]
        __builtin_amdgcn_sched_barrier(0);
        __syncthreads();
    }
    // swap resident biases to decoder cells (2,3)
    for (int i = tid; i < 2 * 512; i += 512) bias_s[i] = bws[2 * 512 + i];
    __syncthreads();
    // decoder entry: h0 cur = h0s[0], h1 cur = h1s[1]

    float fb = (tid < RR * OO) ? fcb[tid & 1] : 0.f;

    // fc: pred[r][o] = h1d(s) . fc_W[o] + fc_b[o]  (threads 0..63 only)
    auto fcOut = [&](int s, int qq) {
        if (tid < RR * OO) {
            int r = tid >> 1, o = tid & 1;
            float a = fb;
            const f16* hrow = &h1s[qq][r][0];
            #pragma unroll
            for (int ccol = 0; ccol < HH; ccol += 8) {
                int csw = ccol ^ SWZ(r);
                f16x8 hv = *(const f16x8*)(hrow + csw);
                f16x8 wv = *(const f16x8*)(&fcws[o * HH + ccol]);
                #pragma unroll
                for (int j = 0; j < 8; ++j) a += (float)hv[j] * (float)wv[j];
            }
            out[((size_t)(r0 + r) * OLEN + s) * OO + o] = a;
        }
    };

    // ============ decoder: 20 steps, 2 barriers/step ============
    // step s (q=s&1): reads h0s[q], h1s[q^1]; writes h0s[q^1] (A), h1s[q] (B).
    // Strictly serial (B(s) needs A(s)'s h0 through the barrier). fc(s-1)
    // folded into A(s): reads h1s[q^1] (A-read-only; next written B(s+1)).
    // bias halves: 0 = cell2, 1 = cell3 (reloaded above).
    for (int s = 0; s < OLEN; ++s) {
        const int q = s & 1;
        // Phase A: gates2 = b2 + h0d(s-1)*DWhh0 + h1d(s-1)*DWih0 -> h0d(s)
        zacc(0);
        if (s > 0) fcOut(s - 1, q ^ 1);  // wave 0 does fc; waves 1-7 proceed
        kq(&h0s[q][0][0], 0);            // DWHH0-0 (preloaded)
        LQ(OFF_DWHH0, 1); kq(&h0s[q][0][0], 1);
        LQ(OFF_DWHH0, 2); kq(&h0s[q][0][0], 2);
        LQ(OFF_DWHH0, 3); kq(&h0s[q][0][0], 3);
        LQ(OFF_DWIH0, 0); kq(&h1s[q ^ 1][0][0], 0);
        LQ(OFF_DWIH0, 1); kq(&h1s[q ^ 1][0][0], 1);
        LQ(OFF_DWIH0, 2); kq(&h1s[q ^ 1][0][0], 2);
        LQ(OFF_DWIH0, 3); kq(&h1s[q ^ 1][0][0], 3);
        LQ(OFF_DWHH1, 0);                // phase-B preload, under actA
        act(c0s, &h0s[q ^ 1][0][0]);
        __builtin_amdgcn_sched_barrier(0);
        __syncthreads();                 // BAR1: h0d(s) published
        // Phase B: gates3 = b3 + h1d(s-1)*DWhh1 + h0d(s)*DWih1 -> h1d(s)
        zacc(1);
        kq(&h1s[q ^ 1][0][0], 0);        // DWHH1-0 (preloaded)
        LQ(OFF_DWHH1, 1); kq(&h1s[q ^ 1][0][0], 1);
        LQ(OFF_DWHH1, 2); kq(&h1s[q ^ 1][0][0], 2);
        LQ(OFF_DWHH1, 3); kq(&h1s[q ^ 1][0][0], 3);
        LQ(OFF_DWIH1, 0); kq(&h0s[q ^ 1][0][0], 0);
        LQ(OFF_DWIH1, 1); kq(&h0s[q ^ 1][0][0], 1);
        LQ(OFF_DWIH1, 2); kq(&h0s[q ^ 1][0][0], 2);
        LQ(OFF_DWIH1, 3); kq(&h0s[q ^ 1][0][0], 3);
        LQ(OFF_DWHH0, 0);                // next step's A preload (dead at s=19, harmless)
        act(c1s, &h1s[q][0][0]);
        __builtin_amdgcn_sched_barrier(0);
        __syncthreads();                 // BAR2: h1d(s) published
    }
    fcOut(OLEN - 1, (OLEN - 1) & 1);     // last step's fc
    #undef LQ
}

extern "C" void kernel_launch(void* const* d_in, const int* in_sizes, int n_in,
                              void* d_out, int out_size, void* d_ws, size_t ws_size,
                              hipStream_t stream) {
    const float* x     = (const float*)d_in[0];
    const float* eWih0 = (const float*)d_in[1];
    const float* eWhh0 = (const float*)d_in[2];
    const float* ebi0  = (const float*)d_in[3];
    const float* ebh0  = (const float*)d_in[4];
    const float* eWih1 = (const float*)d_in[5];
    const float* eWhh1 = (const float*)d_in[6];
    const float* ebi1  = (const float*)d_in[7];
    const float* ebh1  = (const float*)d_in[8];
    const float* dWih0 = (const float*)d_in[9];
    const float* dWhh0 = (const float*)d_in[10];
    const float* dbi0  = (const float*)d_in[11];
    const float* dbh0  = (const float*)d_in[12];
    const float* dWih1 = (const float*)d_in[13];
    const float* dWhh1 = (const float*)d_in[14];
    const float* dbi1  = (const float*)d_in[15];
    const float* dbh1  = (const float*)d_in[16];
    const float* fcW   = (const float*)d_in[17];
    const float* fcb   = (const float*)d_in[18];

    f16*   w16 = (f16*)d_ws;
    float* bws = (float*)((char*)d_ws + OFF_BIAS_B);

    prep_kernel<<<256, 256, 0, stream>>>(eWih0, eWhh0, eWih1, eWhh1,
                                         dWih0, dWhh0, dWih1, dWhh1,
                                         ebi0, ebh0, ebi1, ebh1,
                                         dbi0, dbh0, dbi1, dbh1,
                                         fcW, w16, bws);
    lstm_kernel<<<NB / RR, 512, 0, stream>>>(x, w16, bws, fcb, (float*)d_out);
}

// Round 11
// 1547.568 us; speedup vs baseline: 1.9729x; 1.8570x over previous
//
#include <hip/hip_runtime.h>
#include <stdint.h>
#include <stddef.h>

typedef _Float16 f16;
typedef _Float16 f16x8 __attribute__((ext_vector_type(8)));
typedef float    f32x4 __attribute__((ext_vector_type(4)));

#define NB    16384   // batch
#define TT    100     // encoder steps
#define II    6       // input features
#define HH    128     // hidden
#define OLEN  20      // decoder steps
#define OO    2       // output features
#define RR    64      // batch rows per block

// f16-element offsets into workspace (8 recurrent mats are [512][128] = 65536 f16)
#define OFF_WHH0   0
#define OFF_WIH1   65536
#define OFF_WHH1   131072
#define OFF_DWIH0  196608
#define OFF_DWHH0  262144
#define OFF_DWIH1  327680
#define OFF_DWHH1  393216
#define OFF_WIH0P  458752          // [512][8] zero-padded (K=6 -> 8), prescaled
#define OFF_FCW    462848          // [2][128], NOT prescaled
#define OFF_BIAS_B 926208          // byte offset: 4*512 f32 combined prescaled biases
#define WS_BYTES   934400

#define SWZ(r) (((r) & 15) << 3)   // f16-unit XOR swizzle for h tiles

__device__ __forceinline__ float exp2_(float x) {
#if __has_builtin(__builtin_amdgcn_exp2f)
    return __builtin_amdgcn_exp2f(x);
#else
    return exp2f(x);
#endif
}
__device__ __forceinline__ float rcp_(float x) {
#if __has_builtin(__builtin_amdgcn_rcpf)
    return __builtin_amdgcn_rcpf(x);
#else
    return 1.f / x;
#endif
}

// ---------------- weight prep: fp32 -> f16, gate-prescaled; fuse+prescale biases ----
// gate rows (i,f,o) scaled by -log2(e) so sigmoid(z) = rcp(1+exp2(u));
// gate rows (g)     scaled by 2*log2(e) so tanh(z) = 1 - 2*rcp(1+exp2(u)).
__global__ __launch_bounds__(256) void prep_kernel(
    const float* eWih0, const float* eWhh0, const float* eWih1, const float* eWhh1,
    const float* dWih0, const float* dWhh0, const float* dWih1, const float* dWhh1,
    const float* ebi0,  const float* ebh0,  const float* ebi1,  const float* ebh1,
    const float* dbi0,  const float* dbh0,  const float* dbi1,  const float* dbh1,
    const float* fcW,   f16* w16, float* bws)
{
    const float GS0 = -1.4426950408889634f;   // i, f, o
    const float GS2 =  2.8853900817779268f;   // g
    int i0 = blockIdx.x * blockDim.x + threadIdx.x;
    int stride = gridDim.x * blockDim.x;
    const float* srcs[7] = {eWhh0, eWih1, eWhh1, dWih0, dWhh0, dWih1, dWhh1};
    for (int i = i0; i < 7 * 65536; i += stride) {
        int rem = i & 65535;
        float s = ((rem >> 14) == 2) ? GS2 : GS0;
        w16[i] = (f16)(srcs[i >> 16][rem] * s);
    }
    for (int i = i0; i < 512 * 8; i += stride) {
        int n = i >> 3, k = i & 7;
        float s = ((n >> 7) == 2) ? GS2 : GS0;
        w16[OFF_WIH0P + i] = (k < II) ? (f16)(eWih0[n * II + k] * s) : (f16)0.f;
    }
    for (int i = i0; i < OO * HH; i += stride) w16[OFF_FCW + i] = (f16)fcW[i];
    const float* bia[4] = {ebi0, ebi1, dbi0, dbi1};
    const float* bib[4] = {ebh0, ebh1, dbh0, dbh1};
    for (int i = i0; i < 4 * 512; i += stride) {
        int j = i & 511;
        float s = ((j >> 7) == 2) ? GS2 : GS0;
        bws[i] = (bia[i >> 9][j] + bib[i >> 9][j]) * s;
    }
}

// ---------------- main persistent LSTM kernel: 1 block = 64 batch rows ----------------
// R16 baseline 1606us; R23 half-bank pipelining + fc-fold: 1548us = session
// best, RESTORED here.
// Session conclusions (R17-R26): the kernel is latency/dependency-bound at
// 2 waves/SIMD with a HARD register envelope of ~128 arch + 64 acc:
//  - anti-phase wave arms: regression (code-footprint, no overlap gain)
//  - resident weight banks (VGPR, AGPR-pinned) and dual accumulators: SPILL
//    (allocator will not exceed the 128/128 split; WRITE_SIZE explodes)
//  - 4 waves/SIMD (RR=32 or 1024-thr): requires arch<=64 (HW granule 64,
//    confirmed by occupancy 45-47% in R25/R26) but the inner loop needs
//    acc 32 + bank 16 + A-frags/addressing ~75-85 regs -> always spills.
// R23's schedule: half-bank (32-reg) streamed bursts, each 8-load burst
// covered by the other half's MFMAs or an act; next region's WHH0-L
// preloads under act1; decoder fc(s-1) folded into phase A(s).
__global__ __launch_bounds__(512, 2) void lstm_kernel(
    const float* __restrict__ xg, const f16* __restrict__ wsf,
    const float* __restrict__ bws, const float* __restrict__ fcb,
    float* __restrict__ out)
{
    __shared__ __align__(16) f16 h0s[2][RR][HH];     // 32KB, XOR-swizzled
    __shared__ __align__(16) f16 h1s[2][RR][HH];     // 32KB
    __shared__ __align__(16) f16 xs[2][RR][8];       // 2KB
    __shared__ __align__(16) f16 fcws[OO * HH];      // .5KB
    __shared__ float bias_s[4 * 512];                // 8KB
    __shared__ f32x4 c0s[4][512];                    // 32KB cell-0 state (per-thread slots)
    __shared__ f32x4 c1s[4][512];                    // 32KB cell-1 state -> 138.5KB

    const int tid = threadIdx.x;
    const int w   = tid >> 6;      // wave 0..7 -> hidden cols 16w..16w+15
    const int ln  = tid & 63;
    const int l15 = ln & 15;
    const int lg  = ln >> 4;       // lane k-group
    const int r0  = blockIdx.x * RR;

    // ---- init LDS (note: BOTH h1 buffers zeroed -- region 1 reads h1s[1] as h1(-1))
    for (int i = tid; i < OO * HH; i += 512) fcws[i] = wsf[OFF_FCW + i];
    for (int i = tid; i < 4 * 512; i += 512) bias_s[i] = bws[i];
    for (int i = tid; i < RR * HH; i += 512) {
        h0s[0][0][i] = (f16)0.f;
        h1s[0][0][i] = (f16)0.f;
        h1s[1][0][i] = (f16)0.f;
    }
    {
        const f32x4 z4 = {0.f, 0.f, 0.f, 0.f};
        for (int i = tid; i < 4 * 512; i += 512) {
            (&c0s[0][0])[i] = z4;
            (&c1s[0][0])[i] = z4;
        }
    }
    {   // stage x[t=0]
        int r = tid >> 3, k = tid & 7;
        float v = (k < II) ? xg[((size_t)(r0 + r) * TT + 0) * II + k] : 0.f;
        xs[0][r][k] = (f16)v;
    }

    f32x4 acc[4][4];    // [gate][m] accumulators (64 regs, MFMA C/D)
    f16x8 bankL[4][2];  // [gate][kk=0,1] streamed half-bank (32 regs)
    f16x8 bankH[4][2];  // [gate][kk=2,3] streamed half-bank (32 regs)
    f16x8 bX[4];        // encoder x-weights (16 regs; zero in lanes lg>0)

    {
        const f16x8 z = {};
        #pragma unroll
        for (int g = 0; g < 4; ++g) {
            const int nt = (g << 3) + w;
            bX[g] = (lg == 0)
                ? *(const f16x8*)(wsf + OFF_WIH0P + (size_t)((nt << 4) + l15) * 8)
                : z;
        }
    }

    // stream half of one matrix's B-fragments (kk-major). Offset tied through
    // an empty asm so loads re-execute per call (no hoisting into a
    // persistent spill-prone set -- the R5-R11 failure mode).
    auto loadHalfL = [&](unsigned offElems) {
        unsigned off = offElems;
        asm volatile("" : "+v"(off));
        const f16* W = wsf + off;
        #pragma unroll
        for (int kk = 0; kk < 2; ++kk)
            #pragma unroll
            for (int g = 0; g < 4; ++g) {
                const int nt = (g << 3) + w;
                bankL[g][kk] = *(const f16x8*)(W + (size_t)((nt << 4) + l15) * HH + (kk << 5) + (lg << 3));
            }
    };
    auto loadHalfH = [&](unsigned offElems) {
        unsigned off = offElems;
        asm volatile("" : "+v"(off));
        const f16* W = wsf + off;
        #pragma unroll
        for (int kk = 2; kk < 4; ++kk)
            #pragma unroll
            for (int g = 0; g < 4; ++g) {
                const int nt = (g << 3) + w;
                bankH[g][kk - 2] = *(const f16x8*)(W + (size_t)((nt << 4) + l15) * HH + (kk << 5) + (lg << 3));
            }
    };
    // fence + load: sched_barrier stops the new half-burst's loads from
    // hoisting above the previous consumer of that half (liveness doubling).
    #define LBL(off) do { __builtin_amdgcn_sched_barrier(0); loadHalfL(off); } while (0)
    #define LBH(off) do { __builtin_amdgcn_sched_barrier(0); loadHalfH(off); } while (0)

    auto zacc = [&](int cell) {
        #pragma unroll
        for (int g = 0; g < 4; ++g) {
            float b = bias_s[(cell << 9) | (g << 7) | (w << 4) | l15];
            f32x4 b4 = {b, b, b, b};
            #pragma unroll
            for (int m = 0; m < 4; ++m) acc[g][m] = b4;
        }
    };

    // K=64 half-GEMMs over ALL m-tiles with one half-bank (kk-major)
    auto kRL = [&](const f16* hsrc) {
        #pragma unroll
        for (int kk = 0; kk < 2; ++kk)
            #pragma unroll
            for (int m = 0; m < 4; ++m) {
                int r = (m << 4) + l15;
                int c = ((kk << 5) | (lg << 3)) ^ SWZ(r);
                f16x8 a = *(const f16x8*)(hsrc + (size_t)r * HH + c);
                #pragma unroll
                for (int g = 0; g < 4; ++g)
                    acc[g][m] = __builtin_amdgcn_mfma_f32_16x16x32_f16(a, bankL[g][kk], acc[g][m], 0, 0, 0);
            }
    };
    auto kRH = [&](const f16* hsrc) {
        #pragma unroll
        for (int kk = 2; kk < 4; ++kk)
            #pragma unroll
            for (int m = 0; m < 4; ++m) {
                int r = (m << 4) + l15;
                int c = ((kk << 5) | (lg << 3)) ^ SWZ(r);
                f16x8 a = *(const f16x8*)(hsrc + (size_t)r * HH + c);
                #pragma unroll
                for (int g = 0; g < 4; ++g)
                    acc[g][m] = __builtin_amdgcn_mfma_f32_16x16x32_f16(a, bankH[g][kk - 2], acc[g][m], 0, 0, 0);
            }
    };

    // encoder x-term: zero-padded K=32 MFMA (real K=6 in lanes lg==0); no bank dep
    auto mfx = [&](const f16 (*xsrc)[8]) {
        const f16x8 z = {};
        #pragma unroll
        for (int m = 0; m < 4; ++m) {
            int r = (m << 4) + l15;
            f16x8 a = lg ? z : *(const f16x8*)(&xsrc[r][0]);
            #pragma unroll
            for (int g = 0; g < 4; ++g)
                acc[g][m] = __builtin_amdgcn_mfma_f32_16x16x32_f16(a, bX[g], acc[g][m], 0, 0, 0);
        }
    };

    // gate nonlinearities; c in per-thread LDS slots; h -> hdst (parity-[p^1]
    // buffer, never read in the same region -> race-free).
    auto act = [&](f32x4 (*cs)[512], f16* hdst) {
        const int col = (w << 4) + l15;
        #pragma unroll
        for (int m = 0; m < 4; ++m) {
            f32x4 cold = cs[m][tid];
            f32x4 cnew;
            #pragma unroll
            for (int q = 0; q < 4; ++q) {
                float si = rcp_(1.f + exp2_(acc[0][m][q]));
                float sf = rcp_(1.f + exp2_(acc[1][m][q]));
                float tg = 1.f - 2.f * rcp_(1.f + exp2_(acc[2][m][q]));
                float so = rcp_(1.f + exp2_(acc[3][m][q]));
                float cn = sf * cold[q] + si * tg;
                cnew[q] = cn;
                float hn = so * (1.f - 2.f * rcp_(1.f + exp2_(2.8853900817779268f * cn)));
                int r = (m << 4) + (lg << 2) + q;
                hdst[(size_t)r * HH + (col ^ SWZ(r))] = (f16)hn;
            }
            cs[m][tid] = cnew;
        }
    };

    LBL(OFF_WHH0);       // prologue: region 0's phase-A L-half
    __syncthreads();     // init visible

    // ============ encoder: 100 pipelined regions + tail, 1 barrier each ============
    // region t: phaseA(t):  gates0 = b0 + x(t)*Wih0 + h0s[p]*Whh0 -> h0s[p^1], c0
    //           phaseB(t-1):gates1 = b1 + h1s[p]*Whh1 + h0s[p]*Wih1 -> h1s[p^1], c1
    // (h0(t-1) lives in h0s[p]; h1(t-2) in h1s[p] -- all reads pre-region.)
    // Half-bursts are issued as soon as their half is dead, covered by the
    // other half's MFMAs / act; WHH0-L for region t+1 preloads under act1.
    for (int t = 0; t < TT; ++t) {
        const int p = t & 1;
        float xv = 0.f;
        if (t + 1 < TT && (tid & 7) < II)
            xv = xg[((size_t)(r0 + (tid >> 3)) * TT + (t + 1)) * II + (tid & 7)];
        // phase A (WHH0-L preloaded at end of previous region)
        LBH(OFF_WHH0);                   // H-burst streams under zacc+mfx+kRL
        zacc(0);
        mfx(xs[p]);
        kRL(&h0s[p][0][0]);              // WHH0-L
        LBL(OFF_WHH1);                   // covered by kRH + act0
        kRH(&h0s[p][0][0]);              // WHH0-H
        LBH(OFF_WHH1);                   // covered by act0 + kRL(h1)
        act(c0s, &h0s[p ^ 1][0][0]);
        // phase B of step t-1
        if (t > 0) {
            zacc(1);
            kRL(&h1s[p][0][0]);          // WHH1-L (state term h1(t-2))
            LBL(OFF_WIH1);               // covered by kRH(h1)
            kRH(&h1s[p][0][0]);          // WHH1-H
            LBH(OFF_WIH1);               // covered by kRL(h0)
            kRL(&h0s[p][0][0]);          // WIH1-L (input term h0(t-1), OLD buffer)
            LBL(OFF_WHH0);               // next region's A preload, under kRH+act1
            kRH(&h0s[p][0][0]);          // WIH1-H
            act(c1s, &h1s[p ^ 1][0][0]); // h1(t-1)
        } else {
            LBL(OFF_WHH0);               // region 1's A preload
        }
        if (t + 1 < TT) xs[p ^ 1][tid >> 3][tid & 7] = (f16)xv;
        __builtin_amdgcn_sched_barrier(0);
        __syncthreads();                 // ONE barrier per region
    }
    // tail region: phaseB(99). After loop: h0(99)=h0s[0], h1(98)=h1s[0].
    {
        LBL(OFF_WHH1);
        LBH(OFF_WHH1);
        zacc(1);
        kRL(&h1s[0][0][0]);              // h1(98)
        LBL(OFF_WIH1);
        kRH(&h1s[0][0][0]);
        LBH(OFF_WIH1);
        kRL(&h0s[0][0][0]);              // h0(99)
        LBL(OFF_DWHH0);                  // decoder phase-A preload, under kRH+act1
        kRH(&h0s[0][0][0]);
        act(c1s, &h1s[1][0][0]);         // h1(99) -> h1s[1]
        __builtin_amdgcn_sched_barrier(0);
        __syncthreads();
    }
    // decoder entry: h0 cur = h0s[0], h1 cur = h1s[1]

    float fb = (tid < RR * OO) ? fcb[tid & 1] : 0.f;

    // fc: pred[r][o] = h1d(s) . fc_W[o] + fc_b[o]  (threads 0..127 only)
    auto fcOut = [&](int s, int qq) {
        if (tid < RR * OO) {
            int r = tid >> 1, o = tid & 1;
            float a = fb;
            const f16* hrow = &h1s[qq][r][0];
            #pragma unroll
            for (int ccol = 0; ccol < HH; ccol += 8) {
                int csw = ccol ^ SWZ(r);
                f16x8 hv = *(const f16x8*)(hrow + csw);
                f16x8 wv = *(const f16x8*)(&fcws[o * HH + ccol]);
                #pragma unroll
                for (int j = 0; j < 8; ++j) a += (float)hv[j] * (float)wv[j];
            }
            out[((size_t)(r0 + r) * OLEN + s) * OO + o] = a;
        }
    };

    // ============ decoder: 20 steps, 2 barriers/step ============
    // step s (q=s&1): reads h0s[q], h1s[q^1]; writes h0s[q^1] (A), h1s[q] (B).
    // Strictly serial (B(s) needs A(s)'s h0 through the barrier). fc(s-1) is
    // folded into A(s): it reads h1s[q^1], which A(s) only reads; h1s[q^1] is
    // next written at B(s+1), two barriers later -> race-free.
    for (int s = 0; s < OLEN; ++s) {
        const int q = s & 1;
        // Phase A: gates2 = b2 + h0d(s-1)*DWhh0 + h1d(s-1)*DWih0 -> h0d(s)
        LBH(OFF_DWHH0);                  // streams under zacc+fc+kRL
        zacc(2);
        if (s > 0) fcOut(s - 1, q ^ 1);  // waves 0-1 do fc; waves 2-7 proceed
        kRL(&h0s[q][0][0]);              // DWHH0-L (preloaded)
        LBL(OFF_DWIH0);
        kRH(&h0s[q][0][0]);              // DWHH0-H
        LBH(OFF_DWIH0);
        kRL(&h1s[q ^ 1][0][0]);          // DWIH0-L
        kRH(&h1s[q ^ 1][0][0]);          // DWIH0-H
        LBL(OFF_DWHH1);                  // phase-B preload, under act0
        act(c0s, &h0s[q ^ 1][0][0]);
        __builtin_amdgcn_sched_barrier(0);
        __syncthreads();                 // BAR1: h0d(s) published
        // Phase B: gates3 = b3 + h1d(s-1)*DWhh1 + h0d(s)*DWih1 -> h1d(s)
        LBH(OFF_DWHH1);
        zacc(3);
        kRL(&h1s[q ^ 1][0][0]);          // DWHH1-L (preloaded)
        LBL(OFF_DWIH1);
        kRH(&h1s[q ^ 1][0][0]);          // DWHH1-H
        LBH(OFF_DWIH1);
        kRL(&h0s[q ^ 1][0][0]);          // DWIH1-L
        LBL(OFF_DWHH0);                  // next step's A preload (dead loads at s=19, harmless)
        kRH(&h0s[q ^ 1][0][0]);          // DWIH1-H
        act(c1s, &h1s[q][0][0]);
        __builtin_amdgcn_sched_barrier(0);
        __syncthreads();                 // BAR2: h1d(s) published
    }
    fcOut(OLEN - 1, (OLEN - 1) & 1);     // last step's fc
    #undef LBL
    #undef LBH
}

extern "C" void kernel_launch(void* const* d_in, const int* in_sizes, int n_in,
                              void* d_out, int out_size, void* d_ws, size_t ws_size,
                              hipStream_t stream) {
    const float* x     = (const float*)d_in[0];
    const float* eWih0 = (const float*)d_in[1];
    const float* eWhh0 = (const float*)d_in[2];
    const float* ebi0  = (const float*)d_in[3];
    const float* ebh0  = (const float*)d_in[4];
    const float* eWih1 = (const float*)d_in[5];
    const float* eWhh1 = (const float*)d_in[6];
    const float* ebi1  = (const float*)d_in[7];
    const float* ebh1  = (const float*)d_in[8];
    const float* dWih0 = (const float*)d_in[9];
    const float* dWhh0 = (const float*)d_in[10];
    const float* dbi0  = (const float*)d_in[11];
    const float* dbh0  = (const float*)d_in[12];
    const float* dWih1 = (const float*)d_in[13];
    const float* dWhh1 = (const float*)d_in[14];
    const float* dbi1  = (const float*)d_in[15];
    const float* dbh1  = (const float*)d_in[16];
    const float* fcW   = (const float*)d_in[17];
    const float* fcb   = (const float*)d_in[18];

    f16*   w16 = (f16*)d_ws;
    float* bws = (float*)((char*)d_ws + OFF_BIAS_B);

    prep_kernel<<<256, 256, 0, stream>>>(eWih0, eWhh0, eWih1, eWhh1,
                                         dWih0, dWhh0, dWih1, dWhh1,
                                         ebi0, ebh0, ebi1, ebh1,
                                         dbi0, dbh0, dbi1, dbh1,
                                         fcW, w16, bws);
    lstm_kernel<<<NB / RR, 512, 0, stream>>>(x, w16, bws, fcb, (float*)d_out);
}